// Round 3
// baseline (1551.079 us; speedup 1.0000x reference)
//
#include <hip/hip_runtime.h>
#include <hip/hip_bf16.h>

// Problem constants (from reference)
#define F_DIM 14
#define H1D 16
#define H2D 32
#define H3D 16
#define E_DIM 64
#define TBL   896   // F_DIM * E_DIM floats
#define TBL4  224   // float4 entries per row
#define BLOCK 256
#define GRID  7168  // 7168*256 = 1,835,008 = 224*8192 -> column invariant per thread

// Native clang vector type: __builtin_nontemporal_store requires a vector of
// scalars, not HIP's struct-based float4. Same 16B size/alignment.
typedef float vfloat4 __attribute__((ext_vector_type(4)));

// Math identity: LayerNorm over a singleton dim gives (x-x)/sqrt(eps)*gamma+beta
// = beta, independent of x. So out[b,n,f*64+e] = MLP_f(beta[f])[e] + b4[f,e] +
// emb[f,e] — a 896-float table broadcast over all 400k rows. Pure write-BW
// problem: 1.4336 GB of stores.

__device__ __forceinline__ float gelu_exact(float x) {
    // jax.nn.gelu(approximate=False) = 0.5 * x * (1 + erf(x / sqrt(2)))
    return 0.5f * x * (1.0f + erff(x * 0.70710678118654752440f));
}

__global__ __launch_bounds__(BLOCK) void fused_bcast_kernel(
        const float* __restrict__ beta,
        const float* __restrict__ W1, const float* __restrict__ b1,
        const float* __restrict__ W2, const float* __restrict__ b2,
        const float* __restrict__ W3, const float* __restrict__ b3,
        const float* __restrict__ W4, const float* __restrict__ b4,
        const float* __restrict__ emb,
        vfloat4* __restrict__ out4, int total4) {
    __shared__ float h3s[F_DIM][H3D];        // per-feature MLP output
    __shared__ vfloat4 table4[TBL4];         // the 896-float broadcast row

    const int tid = (int)threadIdx.x;

    // Phase 1: threads 0..13 each run one feature's erf chain (weights are
    // 59 KB total -> L1-resident; ~1k FMA + 48 erf per thread, trivial).
    if (tid < F_DIM) {
        const int f = tid;
        const float v = beta[f];             // LayerNorm(1) output
        float h1[H1D], h2[H2D];
        #pragma unroll
        for (int k = 0; k < H1D; ++k)
            h1[k] = gelu_exact(v * W1[f * H1D + k] + b1[f * H1D + k]);
        #pragma unroll
        for (int j = 0; j < H2D; ++j) {
            float acc = b2[f * H2D + j];
            #pragma unroll
            for (int k = 0; k < H1D; ++k)
                acc += h1[k] * W2[(f * H1D + k) * H2D + j];
            h2[j] = gelu_exact(acc);
        }
        #pragma unroll
        for (int j = 0; j < H3D; ++j) {
            float acc = b3[f * H3D + j];
            #pragma unroll
            for (int k = 0; k < H2D; ++k)
                acc += h2[k] * W3[(f * H2D + k) * H3D + j];
            h3s[f][j] = gelu_exact(acc);
        }
    }
    __syncthreads();

    // Phase 2: 896 table entries over 256 threads (same accumulation order as
    // the round-1-validated version -> bit-identical result).
    float* table = (float*)table4;
    for (int g = tid; g < TBL; g += BLOCK) {
        const int f = g >> 6;
        const int e = g & 63;
        float acc = b4[g] + emb[g];
        #pragma unroll
        for (int m = 0; m < H3D; ++m)
            acc += h3s[f][m] * W4[(f * H3D + m) * E_DIM + e];
        table[g] = acc;
    }
    __syncthreads();

    // Phase 3: broadcast. stride % 224 == 0 -> each thread's column is
    // loop-invariant: one LDS read, then a pure streaming-store loop.
    int idx = (int)(blockIdx.x * BLOCK + tid);
    const int c = idx % TBL4;
    const vfloat4 tv = table4[c];
    const int stride = GRID * BLOCK;
    for (; idx < total4; idx += stride)
        __builtin_nontemporal_store(tv, &out4[idx]);
}

extern "C" void kernel_launch(void* const* d_in, const int* in_sizes, int n_in,
                              void* d_out, int out_size, void* d_ws, size_t ws_size,
                              hipStream_t stream) {
    // setup_inputs order: x, gamma, beta, W1, b1, W2, b2, W3, b3, W4, b4, emb
    const float* beta = (const float*)d_in[2];
    const float* W1   = (const float*)d_in[3];
    const float* b1   = (const float*)d_in[4];
    const float* W2   = (const float*)d_in[5];
    const float* b2   = (const float*)d_in[6];
    const float* W3   = (const float*)d_in[7];
    const float* b3   = (const float*)d_in[8];
    const float* W4   = (const float*)d_in[9];
    const float* b4   = (const float*)d_in[10];
    const float* emb  = (const float*)d_in[11];

    const int total4 = out_size / 4;   // 89,600,000 float4 stores
    fused_bcast_kernel<<<GRID, BLOCK, 0, stream>>>(
        beta, W1, b1, W2, b2, W3, b3, W4, b4, emb,
        (vfloat4*)d_out, total4);
}

// Round 4
// 1432.462 us; speedup vs baseline: 1.0828x; 1.0828x over previous
//
#include <hip/hip_runtime.h>
#include <hip/hip_bf16.h>

// Problem constants (from reference)
#define F_DIM 14
#define H1D 16
#define H2D 32
#define H3D 16
#define E_DIM 64
// table size = F_DIM * E_DIM = 896 floats = 224 float4

// Math identity: LayerNorm over a singleton dim gives (x-x)/sqrt(eps)*gamma+beta
// = beta, independent of x. So out[b,n,f*64+e] = MLP_f(beta[f])[e] + b4[f,e] +
// emb[f,e] — a 896-float table broadcast over all 400k rows. Pure write-BW
// problem: 1.4336 GB of stores.
//
// R3 lesson: nontemporal stores and per-block fused table recompute both
// regressed (1444 -> 1551 us). Plain cached dwordx4 stores + one-block table
// kernel is the measured-best structure.

__device__ __forceinline__ float gelu_exact(float x) {
    // jax.nn.gelu(approximate=False) = 0.5 * x * (1 + erf(x / sqrt(2)))
    return 0.5f * x * (1.0f + erff(x * 0.70710678118654752440f));
}

// Kernel 1: compute the 896-entry table. One block, 896 threads; thread t
// handles (f = t/64, e = t%64); each thread redundantly runs its feature's
// ~1k-MAC erf chain — trivial cost, weights are L1-resident.
__global__ void build_table_kernel(const float* __restrict__ beta,
                                   const float* __restrict__ W1,
                                   const float* __restrict__ b1,
                                   const float* __restrict__ W2,
                                   const float* __restrict__ b2,
                                   const float* __restrict__ W3,
                                   const float* __restrict__ b3,
                                   const float* __restrict__ W4,
                                   const float* __restrict__ b4,
                                   const float* __restrict__ emb,
                                   float* __restrict__ table) {
    const int tid = (int)threadIdx.x;          // 0..895
    const int f = tid >> 6;                    // feature index
    const int e = tid & 63;                    // embedding index
    if (f >= F_DIM) return;

    const float v = beta[f];                   // the LayerNorm(1) output

    float h1[H1D], h2[H2D], h3[H3D];
    #pragma unroll
    for (int k = 0; k < H1D; ++k)
        h1[k] = gelu_exact(v * W1[f * H1D + k] + b1[f * H1D + k]);

    #pragma unroll
    for (int j = 0; j < H2D; ++j) {
        float acc = b2[f * H2D + j];
        #pragma unroll
        for (int k = 0; k < H1D; ++k)
            acc += h1[k] * W2[(f * H1D + k) * H2D + j];
        h2[j] = gelu_exact(acc);
    }

    #pragma unroll
    for (int j = 0; j < H3D; ++j) {
        float acc = b3[f * H3D + j];
        #pragma unroll
        for (int k = 0; k < H2D; ++k)
            acc += h2[k] * W3[(f * H2D + k) * H3D + j];
        h3[j] = gelu_exact(acc);
    }

    float acc = b4[f * E_DIM + e] + emb[f * E_DIM + e];
    #pragma unroll
    for (int m = 0; m < H3D; ++m)
        acc += h3[m] * W4[(f * H3D + m) * E_DIM + e];

    table[tid] = acc;
}

// Kernel 2: broadcast the table over all B*N rows.
// 896 floats/row = 224 float4/row. Grid chosen so (gridDim*blockDim) % 224 == 0,
// so each thread's column (idx % 224) is invariant across grid-stride iterations:
// one table read per thread (L1/L2-cached), then a pure coalesced 16B/lane
// store loop through the normal cache path (no nt — measured faster).
__global__ __launch_bounds__(256) void broadcast_kernel(const float4* __restrict__ table4,
                                                        float4* __restrict__ out4,
                                                        int total4) {
    const int stride = (int)(gridDim.x * blockDim.x);        // multiple of 224
    int idx = (int)(blockIdx.x * blockDim.x + threadIdx.x);
    const int c = idx % 224;                                 // constant per thread
    const float4 tv = table4[c];
    for (; idx < total4; idx += stride)
        out4[idx] = tv;
}

extern "C" void kernel_launch(void* const* d_in, const int* in_sizes, int n_in,
                              void* d_out, int out_size, void* d_ws, size_t ws_size,
                              hipStream_t stream) {
    // setup_inputs order: x, gamma, beta, W1, b1, W2, b2, W3, b3, W4, b4, emb
    const float* beta = (const float*)d_in[2];
    const float* W1   = (const float*)d_in[3];
    const float* b1   = (const float*)d_in[4];
    const float* W2   = (const float*)d_in[5];
    const float* b2   = (const float*)d_in[6];
    const float* W3   = (const float*)d_in[7];
    const float* b3   = (const float*)d_in[8];
    const float* W4   = (const float*)d_in[9];
    const float* b4   = (const float*)d_in[10];
    const float* emb  = (const float*)d_in[11];

    float* out = (float*)d_out;

    // Table scratch: prefer d_ws; fall back to the head of d_out (row 0 of the
    // output IS the table, and the broadcast rewrites it with identical values).
    float* table = (ws_size >= (size_t)(F_DIM * E_DIM * sizeof(float)))
                       ? (float*)d_ws : out;

    build_table_kernel<<<1, F_DIM * E_DIM, 0, stream>>>(
        beta, W1, b1, W2, b2, W3, b3, W4, b4, emb, table);

    const int total4 = out_size / 4;          // 89,600,000 float4 stores
    const int blocks = 3584;                  // 3584*256 = 917504 = 224*4096
    broadcast_kernel<<<blocks, 256, 0, stream>>>(
        (const float4*)table, (float4*)out, total4);
}